// Round 20
// baseline (806.699 us; speedup 1.0000x reference)
//
#include <hip/hip_runtime.h>
#include <hip/hip_fp8.h>
#include <hip/hip_cooperative_groups.h>

namespace cg = cooperative_groups;

#define NN 6144
#define F1 128
#define SSCALE 512.0f
#define PSCALE_INV (1.0f / 128.0f)
#define FSCALE 0.25f  // 128/512
#define CKSPLIT 8
#define CKC 768       // k per block
#define MBROWS 192    // rows per block

typedef __attribute__((ext_vector_type(4))) float f32x4;

__device__ __forceinline__ unsigned int pack4_fp8(float a, float b, float c, float d) {
#if __has_builtin(__builtin_amdgcn_cvt_pk_fp8_f32)
  int v = __builtin_amdgcn_cvt_pk_fp8_f32(a, b, 0, false);
  v = __builtin_amdgcn_cvt_pk_fp8_f32(c, d, v, true);
  return (unsigned int)v;
#else
  __hip_fp8_e4m3 qa(a), qb(b), qc(c), qd(d);
  return (unsigned)qa.__x | ((unsigned)qb.__x << 8) | ((unsigned)qc.__x << 16) |
         ((unsigned)qd.__x << 24);
#endif
}
__device__ __forceinline__ unsigned char f2fp8(float a) {
#if __has_builtin(__builtin_amdgcn_cvt_pk_fp8_f32)
  return (unsigned char)(__builtin_amdgcn_cvt_pk_fp8_f32(a, a, 0, false) & 0xFF);
#else
  __hip_fp8_e4m3 q(a);
  return q.__x;
#endif
}
template <int SEL>
__device__ __forceinline__ float fp8tof(unsigned int word) {
#if __has_builtin(__builtin_amdgcn_cvt_f32_fp8)
  return __builtin_amdgcn_cvt_f32_fp8((int)word, SEL);
#else
  __hip_fp8_e4m3 q;
  q.__x = (unsigned char)(word >> (8 * SEL));
  return (float)q;
#endif
}

// async global->LDS, 16B per lane; lds dest = base + lane*16 (wave-uniform base)
__device__ __forceinline__ void gload16(const void* g, void* l) {
  __builtin_amdgcn_global_load_lds(
      (const __attribute__((address_space(1))) unsigned int*)g,
      (__attribute__((address_space(3))) unsigned int*)l, 16, 0, 0);
}

// ---------------------------------------------------------------- prep
__global__ __launch_bounds__(128) void prep_kernel(
    const float* __restrict__ x5, const float* __restrict__ x0,
    const float* __restrict__ W_gat, const float* __restrict__ b_gat,
    const float* __restrict__ W_lin, const float* __restrict__ b_lin,
    float* __restrict__ hT, float* __restrict__ sq,
    float* __restrict__ Tx0, unsigned char* __restrict__ XT0) {
  int i = blockIdx.x;
  int t = threadIdx.x;
  __shared__ float xs[64];
  __shared__ float x5s[3];
  __shared__ float hs[6];
  if (t < 3) x5s[t] = x5[i * 3 + t];
  if (t < 64) xs[t] = x0[(size_t)i * 64 + t];
  __syncthreads();
  if (t < 6) {
    float a = b_gat[t];
#pragma unroll
    for (int k = 0; k < 3; k++) a += x5s[k] * W_gat[k * 6 + t];
    a = fmaxf(a, 0.f);
    hs[t] = a;
    hT[(size_t)t * NN + i] = a;
  }
  __syncthreads();
  if (t == 0) {
    float s = 0.f;
#pragma unroll
    for (int k = 0; k < 6; k++) s += hs[k] * hs[k];
    sq[i] = s;
  }
  float a = b_lin[t];
#pragma unroll 16
  for (int k = 0; k < 64; k++) a += xs[k] * W_lin[k * 128 + t];
  a = fmaxf(a, 0.f);
  Tx0[(size_t)i * F1 + t] = a;
  XT0[(size_t)t * NN + i] = f2fp8(a);
}

// ---------------------------------------------------------------- prob (8 rows/block)
__global__ __launch_bounds__(256) void prob_kernel(
    const float* __restrict__ hT, const float* __restrict__ sq,
    float* __restrict__ P, float* __restrict__ dinv) {
  int i0 = blockIdx.x * 8;
  int t = threadIdx.x;
  float h[8][6], si[8];
#pragma unroll
  for (int q = 0; q < 8; q++) {
    si[q] = sq[i0 + q];
#pragma unroll
    for (int r = 0; r < 6; r++) h[q][r] = hT[(size_t)r * NN + i0 + q];
  }
  float acc[8] = {0.f, 0.f, 0.f, 0.f, 0.f, 0.f, 0.f, 0.f};
  for (int j4 = t; j4 < NN / 4; j4 += 256) {
    int j = j4 * 4;
    float4 qv = *(const float4*)(sq + j);
    float4 v0 = *(const float4*)(hT + j);
    float4 v1 = *(const float4*)(hT + NN + j);
    float4 v2 = *(const float4*)(hT + 2 * NN + j);
    float4 v3 = *(const float4*)(hT + 3 * NN + j);
    float4 v4 = *(const float4*)(hT + 4 * NN + j);
    float4 v5 = *(const float4*)(hT + 5 * NN + j);
#pragma unroll
    for (int q = 0; q < 8; q++) {
      float p[4];
#pragma unroll
      for (int m = 0; m < 4; m++) {
        float dot = h[q][0] * ((const float*)&v0)[m] + h[q][1] * ((const float*)&v1)[m] +
                    h[q][2] * ((const float*)&v2)[m] + h[q][3] * ((const float*)&v3)[m] +
                    h[q][4] * ((const float*)&v4)[m] + h[q][5] * ((const float*)&v5)[m];
        float d = si[q] + ((const float*)&qv)[m] - 2.f * dot;
        p[m] = __expf(-0.5f * d);
        if (j + m != i0 + q) acc[q] += p[m];
      }
      float4 pv; pv.x = p[0]; pv.y = p[1]; pv.z = p[2]; pv.w = p[3];
      *(float4*)(P + (size_t)(i0 + q) * NN + j) = pv;
    }
  }
  __shared__ float red[256];
#pragma unroll
  for (int q = 0; q < 8; q++) {
    red[t] = acc[q];
    __syncthreads();
    for (int s = 128; s > 0; s >>= 1) {
      if (t < s) red[t] += red[t + s];
      __syncthreads();
    }
    if (t == 0) {
      float deg = red[0];
      dinv[i0 + q] = deg > 0.f ? rsqrtf(deg) : 0.f;
    }
    __syncthreads();
  }
}

// ---------------------------------------------------------------- smat (fp8, 8 rows/block)
__global__ __launch_bounds__(256) void smat_kernel(
    const float* __restrict__ hT, const float* __restrict__ sq,
    const float* __restrict__ dinv, unsigned int* __restrict__ S32) {
  int i0 = blockIdx.x * 8;
  int t = threadIdx.x;
  float h[8][6], si[8], dis[8];
#pragma unroll
  for (int q = 0; q < 8; q++) {
    si[q] = sq[i0 + q];
    dis[q] = -SSCALE * dinv[i0 + q];
#pragma unroll
    for (int r = 0; r < 6; r++) h[q][r] = hT[(size_t)r * NN + i0 + q];
  }
  for (int j4 = t; j4 < NN / 4; j4 += 256) {
    int j = j4 * 4;
    float4 qv = *(const float4*)(sq + j);
    float4 dj = *(const float4*)(dinv + j);
    float4 v0 = *(const float4*)(hT + j);
    float4 v1 = *(const float4*)(hT + NN + j);
    float4 v2 = *(const float4*)(hT + 2 * NN + j);
    float4 v3 = *(const float4*)(hT + 3 * NN + j);
    float4 v4 = *(const float4*)(hT + 4 * NN + j);
    float4 v5 = *(const float4*)(hT + 5 * NN + j);
#pragma unroll
    for (int q = 0; q < 8; q++) {
      float s[4];
#pragma unroll
      for (int m = 0; m < 4; m++) {
        float dot = h[q][0] * ((const float*)&v0)[m] + h[q][1] * ((const float*)&v1)[m] +
                    h[q][2] * ((const float*)&v2)[m] + h[q][3] * ((const float*)&v3)[m] +
                    h[q][4] * ((const float*)&v4)[m] + h[q][5] * ((const float*)&v5)[m];
        float d = si[q] + ((const float*)&qv)[m] - 2.f * dot;
        float p = __expf(-0.5f * d);
        s[m] = dis[q] * p * ((const float*)&dj)[m];
        if (j + m == i0 + q) s[m] = 0.f;
      }
      S32[(size_t)(i0 + q) * (NN / 4) + j4] = pack4_fp8(s[0], s[1], s[2], s[3]);
    }
  }
}

// ---------------------------------------------------------------- persistent cooperative chain
// 256 blocks x 512 thr (8 waves), 1 block/CU. Block owns S-slice (192 rows x
// 768 k, fp8) staged ONCE in 144KB LDS (XOR-16B-unit swizzle by row&15).
// Per step: 12x {stage 8KB XT chunk -> MFMA} -> fp8 partial -> grid.sync ->
// in-kernel finalize (24 rows/block) -> grid.sync.
__global__ __launch_bounds__(512, 1) void chain_kernel(
    const unsigned char* __restrict__ S, unsigned char* __restrict__ XTa,
    unsigned char* __restrict__ XTb, unsigned char* __restrict__ partial,
    float* __restrict__ Tx) {
  __shared__ unsigned char Sl[MBROWS * CKC];  // 147456 B
  __shared__ unsigned char Bs[128 * 64];      // 8192 B
  cg::grid_group grid = cg::this_grid();
  const int TOT4 = NN * F1 / 4;
  int b = blockIdx.x;
  int mb = b & 31;
  int ks = b >> 5;
  int row0g = mb * MBROWS;
  int k0 = ks * CKC;
  int t = threadIdx.x;
  int v = t >> 6;
  int l = t & 63;
  int wr = v >> 1;  // 0..3 -> 48-row band
  int wc = v & 1;   // 0..1 -> 64-col band
  int lr = l & 15, lg = l >> 4;

  // ---- prologue: stage S slice into LDS (pre-swizzled source)
  for (int c = 0; c < 18; c++) {
    int B0 = (v * 18 + c) * 1024;
    int phys = B0 + 16 * l;
    int row = phys / CKC;
    int up = (phys % CKC) >> 4;
    int ul = up ^ (row & 15);
    gload16(S + (size_t)(row0g + row) * NN + k0 + ul * 16, &Sl[B0]);
  }

  for (int k = 1; k <= 8; k++) {
    const unsigned char* xin = (k & 1) ? XTa : XTb;
    unsigned char* xout = (k & 1) ? XTb : XTa;

    f32x4 acc[3][4];
#pragma unroll
    for (int i = 0; i < 3; i++)
#pragma unroll
      for (int j = 0; j < 4; j++) acc[i][j] = (f32x4){0.f, 0.f, 0.f, 0.f};

    for (int kkc = 0; kkc < 12; kkc++) {
      {
        int B0 = v * 1024;
        int phys = B0 + 16 * l;
        int f = phys >> 6;
        int up = (phys & 63) >> 4;
        int ul = up ^ ((f >> 1) & 3);
        gload16(xin + (size_t)f * NN + k0 + kkc * 64 + ul * 16, &Bs[B0]);
      }
      asm volatile("s_waitcnt vmcnt(0)" ::: "memory");
      asm volatile("s_barrier" ::: "memory");
#pragma unroll
      for (int kk2 = 0; kk2 < 64; kk2 += 32) {
        int koff = kk2 + lg * 8;
        int koffA = kkc * 64 + koff;
        long af[3], bfr[4];
#pragma unroll
        for (int i = 0; i < 3; i++) {
          int r = wr * 48 + i * 16 + lr;
          int pa = r * CKC + 16 * ((koffA >> 4) ^ (r & 15)) + (koffA & 15);
          af[i] = *(const long*)(&Sl[pa]);
        }
#pragma unroll
        for (int j = 0; j < 4; j++) {
          int f = wc * 64 + j * 16 + lr;
          int pb = f * 64 + 16 * ((koff >> 4) ^ ((f >> 1) & 3)) + (koff & 15);
          bfr[j] = *(const long*)(&Bs[pb]);
        }
#pragma unroll
        for (int i = 0; i < 3; i++)
#pragma unroll
          for (int j = 0; j < 4; j++)
            acc[i][j] = __builtin_amdgcn_mfma_f32_16x16x32_fp8_fp8(
                af[i], bfr[j], acc[i][j], 0, 0, 0);
      }
      asm volatile("s_barrier" ::: "memory");
    }

    // write fp8 partial (C/D layout: col = lane&15, row-in-16 = lg*4 + r)
    unsigned char* pbase = partial + (size_t)ks * NN * F1;
#pragma unroll
    for (int i = 0; i < 3; i++) {
      int rowo = row0g + wr * 48 + i * 16 + lg * 4;
#pragma unroll
      for (int j = 0; j < 4; j++) {
        int colo = wc * 64 + j * 16 + lr;
#pragma unroll
        for (int rr = 0; rr < 4; rr++)
          pbase[(size_t)(rowo + rr) * F1 + colo] = f2fp8(acc[i][j][rr] * PSCALE_INV);
      }
    }

    grid.sync();

    // finalize: block reduces rows [b*24, b*24+24)
    if (t < 192) {
      int rquad = t >> 5;
      int c4 = t & 31;
      int rb = b * 24 + rquad * 4;
      const unsigned int* p32 = (const unsigned int*)partial;
      const float4* prevprev =
          (const float4*)(Tx + (size_t)(k >= 2 ? k - 2 : 0) * NN * F1);
      float4* TxOut = (float4*)(Tx + (size_t)k * NN * F1);
      unsigned int* XT8 = (unsigned int*)xout;
      float g[4][4];
#pragma unroll
      for (int rr = 0; rr < 4; rr++) {
        int fidx = (rb + rr) * 32 + c4;
        float a0 = 0.f, a1 = 0.f, a2 = 0.f, a3 = 0.f;
#pragma unroll
        for (int s = 0; s < CKSPLIT; s++) {
          unsigned int vv = p32[(size_t)s * TOT4 + fidx];
          a0 += fp8tof<0>(vv); a1 += fp8tof<1>(vv);
          a2 += fp8tof<2>(vv); a3 += fp8tof<3>(vv);
        }
        a0 *= FSCALE; a1 *= FSCALE; a2 *= FSCALE; a3 *= FSCALE;
        if (k >= 2) {
          float4 q = prevprev[fidx];
          a0 = 2.f * a0 - q.x; a1 = 2.f * a1 - q.y;
          a2 = 2.f * a2 - q.z; a3 = 2.f * a3 - q.w;
        }
        float4 o; o.x = a0; o.y = a1; o.z = a2; o.w = a3;
        TxOut[fidx] = o;
        g[rr][0] = a0; g[rr][1] = a1; g[rr][2] = a2; g[rr][3] = a3;
      }
#pragma unroll
      for (int j = 0; j < 4; j++) {
        unsigned int pk = pack4_fp8(g[0][j], g[1][j], g[2][j], g[3][j]);
        XT8[(((size_t)(c4 * 4 + j)) * NN + rb) >> 2] = pk;
      }
    }

    grid.sync();
  }
}

// ---------------------------------------------------------------- epilogue (384 blocks x 16 rows)
__global__ __launch_bounds__(256) void out_kernel(
    const float* __restrict__ Tx, const float* __restrict__ Wcat,
    const float* __restrict__ b3, const float* __restrict__ b6,
    const float* __restrict__ b9,
    const float* __restrict__ Wl, const float* __restrict__ bl,
    float* __restrict__ x_out, float* __restrict__ last_out) {
  __shared__ float WS[128 * 48];
  __shared__ float TxS[16][129];
  __shared__ float lo[16][48];
  __shared__ float lg[16][16];
  __shared__ float le[16][16];
  __shared__ float WlS[48 * 16];
  __shared__ float blS[16];
  int t = threadIdx.x;
  int row0 = blockIdx.x * 16;
  int rg = t >> 4;
  int cg2 = t & 15;
  float acc[3] = {0.f, 0.f, 0.f};
  for (int i = t; i < 768; i += 256) WlS[i] = Wl[i];
  if (t < 16) blS[t] = bl[t];
  for (int k = 0; k < 9; k++) {
    for (int i = t; i < 6144; i += 256) WS[i] = Wcat[k * 6144 + i];
    for (int i = t; i < 2048; i += 256) {
      int r = i >> 7, j = i & 127;
      TxS[r][j] = Tx[((size_t)k * NN + row0 + r) * F1 + j];
    }
    __syncthreads();
#pragma unroll 4
    for (int j = 0; j < 128; j++) {
      float t0 = TxS[rg][j];
      const float* wp = &WS[j * 48 + 3 * cg2];
      acc[0] += t0 * wp[0]; acc[1] += t0 * wp[1]; acc[2] += t0 * wp[2];
    }
    __syncthreads();
  }
#pragma unroll
  for (int cc = 0; cc < 3; cc++) {
    int c = 3 * cg2 + cc;
    float bias = c < 16 ? b3[c] : (c < 32 ? b6[c - 16] : b9[c - 32]);
    float v = acc[cc] + bias;
    lo[rg][c] = v;
    last_out[(size_t)(row0 + rg) * 48 + c] = v;
  }
  __syncthreads();
  {
    int r = t >> 4, c = t & 15;
    float lgt = blS[c];
#pragma unroll 8
    for (int j = 0; j < 48; j++) lgt += lo[r][j] * WlS[j * 16 + c];
    lg[r][c] = lgt;
  }
  __syncthreads();
  {
    int r = t >> 4, c = t & 15;
    float mx = lg[r][0];
#pragma unroll
    for (int j = 1; j < 16; j++) mx = fmaxf(mx, lg[r][j]);
    le[r][c] = __expf(lg[r][c] - mx);
  }
  __syncthreads();
  {
    int r = t >> 4, c = t & 15;
    float sum = 0.f;
#pragma unroll
    for (int j = 0; j < 16; j++) sum += le[r][j];
    x_out[(size_t)(row0 + r) * 16 + c] = le[r][c] / sum;
  }
}

// ---------------------------------------------------------------- misc copies + Wcat build
__global__ __launch_bounds__(256) void copy_kernel(
    const int* __restrict__ tr, const int* __restrict__ val,
    const float* __restrict__ x0, float* __restrict__ tr_out,
    float* __restrict__ val_out, float* __restrict__ x0_out,
    const float* __restrict__ W3, const float* __restrict__ W6,
    const float* __restrict__ W9, float* __restrict__ Wcat) {
  int i = blockIdx.x * 256 + threadIdx.x;
  if (i < 4000) tr_out[i] = (float)tr[i];
  if (i < 1000) val_out[i] = (float)val[i];
  if (i < NN * 64) x0_out[i] = x0[i];
  if (i < 9 * 128 * 48) {
    int c = i % 48;
    int j = (i / 48) % 128;
    int k = i / (48 * 128);
    float v = 0.f;
    if (c < 16) {
      if (k < 3) v = W3[(k * 128 + j) * 16 + c];
    } else if (c < 32) {
      if (k < 6) v = W6[(k * 128 + j) * 16 + (c - 16)];
    } else {
      v = W9[(k * 128 + j) * 16 + (c - 32)];
    }
    Wcat[i] = v;
  }
}

extern "C" void kernel_launch(void* const* d_in, const int* in_sizes, int n_in,
                              void* d_out, int out_size, void* d_ws, size_t ws_size,
                              hipStream_t stream) {
  const float* x5 = (const float*)d_in[0];
  const float* x0 = (const float*)d_in[1];
  const int* tr = (const int*)d_in[2];
  const int* val = (const int*)d_in[3];
  const float* W_gat = (const float*)d_in[4];
  const float* b_gat = (const float*)d_in[5];
  const float* W_lin = (const float*)d_in[6];
  const float* b_lin = (const float*)d_in[7];
  const float* W3 = (const float*)d_in[8];
  const float* b3 = (const float*)d_in[9];
  const float* W6 = (const float*)d_in[10];
  const float* b6 = (const float*)d_in[11];
  const float* W9 = (const float*)d_in[12];
  const float* b9 = (const float*)d_in[13];
  const float* Wl = (const float*)d_in[14];
  const float* bl = (const float*)d_in[15];

  float* out = (float*)d_out;
  float* x_out = out;
  float* tr_out = x_out + (size_t)NN * 16;
  float* val_out = tr_out + 4000;
  float* P = val_out + 1000;
  float* last_out = P + (size_t)NN * NN;
  float* x0_out = last_out + (size_t)NN * 48;

  char* w = (char*)d_ws;
  unsigned char* Sb = (unsigned char*)w;    w += (size_t)NN * NN;
  float* Tx = (float*)w;                    w += (size_t)9 * NN * F1 * 4;
  unsigned char* partial = (unsigned char*)w; w += (size_t)CKSPLIT * NN * F1;
  unsigned char* XTa = (unsigned char*)w;   w += (size_t)NN * F1;
  unsigned char* XTb = (unsigned char*)w;   w += (size_t)NN * F1;
  float* hT = (float*)w;                    w += (size_t)6 * NN * 4;
  float* sq = (float*)w;                    w += (size_t)NN * 4;
  float* dinv = (float*)w;                  w += (size_t)NN * 4;
  float* Wcat = (float*)w;                  w += (size_t)9 * 128 * 48 * 4;

  prep_kernel<<<NN, 128, 0, stream>>>(x5, x0, W_gat, b_gat, W_lin, b_lin, hT, sq,
                                      Tx, XTa);
  prob_kernel<<<NN / 8, 256, 0, stream>>>(hT, sq, P, dinv);
  smat_kernel<<<NN / 8, 256, 0, stream>>>(hT, sq, dinv, (unsigned int*)Sb);
  copy_kernel<<<1536, 256, 0, stream>>>(tr, val, x0, tr_out, val_out, x0_out,
                                        W3, W6, W9, Wcat);

  {
    void* args[] = {(void*)&Sb, (void*)&XTa, (void*)&XTb, (void*)&partial,
                    (void*)&Tx};
    hipLaunchCooperativeKernel((void*)chain_kernel, dim3(256), dim3(512), args,
                               0, stream);
  }

  out_kernel<<<384, 256, 0, stream>>>(Tx, Wcat, b3, b6, b9, Wl, bl, x_out,
                                      last_out);
}

// Round 21
// 294.402 us; speedup vs baseline: 2.7401x; 2.7401x over previous
//
#include <hip/hip_runtime.h>
#include <hip/hip_fp8.h>

#define NN 6144
#define F1 128
#define KSPLIT 16
#define KC 384
#define BK 64
#define NSTEPS (KC / BK)
#define SSCALE 512.0f
#define PSCALE_INV (1.0f / 128.0f)
#define FSCALE 0.25f  // 128/512

typedef __attribute__((ext_vector_type(4))) float f32x4;

__device__ __forceinline__ unsigned short f2bf(float f) {
  unsigned int u = __float_as_uint(f);
  unsigned int r = (u + 0x7fffu + ((u >> 16) & 1u)) >> 16;
  return (unsigned short)r;
}

__device__ __forceinline__ unsigned int pack4_fp8(float a, float b, float c, float d) {
#if __has_builtin(__builtin_amdgcn_cvt_pk_fp8_f32)
  int v = __builtin_amdgcn_cvt_pk_fp8_f32(a, b, 0, false);
  v = __builtin_amdgcn_cvt_pk_fp8_f32(c, d, v, true);
  return (unsigned int)v;
#else
  __hip_fp8_e4m3 qa(a), qb(b), qc(c), qd(d);
  return (unsigned)qa.__x | ((unsigned)qb.__x << 8) | ((unsigned)qc.__x << 16) |
         ((unsigned)qd.__x << 24);
#endif
}
__device__ __forceinline__ unsigned char f2fp8(float a) {
#if __has_builtin(__builtin_amdgcn_cvt_pk_fp8_f32)
  return (unsigned char)(__builtin_amdgcn_cvt_pk_fp8_f32(a, a, 0, false) & 0xFF);
#else
  __hip_fp8_e4m3 q(a);
  return q.__x;
#endif
}
template <int SEL>
__device__ __forceinline__ float fp8tof(unsigned int word) {
#if __has_builtin(__builtin_amdgcn_cvt_f32_fp8)
  return __builtin_amdgcn_cvt_f32_fp8((int)word, SEL);
#else
  __hip_fp8_e4m3 q;
  q.__x = (unsigned char)(word >> (8 * SEL));
  return (float)q;
#endif
}

// async global->LDS, 16B per lane; lds dest = base + lane*16 (wave-uniform base)
__device__ __forceinline__ void gload16(const void* g, void* l) {
  __builtin_amdgcn_global_load_lds(
      (const __attribute__((address_space(1))) unsigned int*)g,
      (__attribute__((address_space(3))) unsigned int*)l, 16, 0, 0);
}

// ---------------------------------------------------------------- prep
__global__ __launch_bounds__(128) void prep_kernel(
    const float* __restrict__ x5, const float* __restrict__ x0,
    const float* __restrict__ W_gat, const float* __restrict__ b_gat,
    const float* __restrict__ W_lin, const float* __restrict__ b_lin,
    float* __restrict__ hT, float* __restrict__ sq,
    float* __restrict__ Tx0, unsigned char* __restrict__ XT0) {
  int i = blockIdx.x;
  int t = threadIdx.x;
  __shared__ float xs[64];
  __shared__ float x5s[3];
  __shared__ float hs[6];
  if (t < 3) x5s[t] = x5[i * 3 + t];
  if (t < 64) xs[t] = x0[(size_t)i * 64 + t];
  __syncthreads();
  if (t < 6) {
    float a = b_gat[t];
#pragma unroll
    for (int k = 0; k < 3; k++) a += x5s[k] * W_gat[k * 6 + t];
    a = fmaxf(a, 0.f);
    hs[t] = a;
    hT[(size_t)t * NN + i] = a;
  }
  __syncthreads();
  if (t == 0) {
    float s = 0.f;
#pragma unroll
    for (int k = 0; k < 6; k++) s += hs[k] * hs[k];
    sq[i] = s;
  }
  float a = b_lin[t];
#pragma unroll 16
  for (int k = 0; k < 64; k++) a += xs[k] * W_lin[k * 128 + t];
  a = fmaxf(a, 0.f);
  Tx0[(size_t)i * F1 + t] = a;
  XT0[(size_t)t * NN + i] = f2fp8(a);
}

// ---------------------------------------------------------------- prob (8 rows/block)
__global__ __launch_bounds__(256) void prob_kernel(
    const float* __restrict__ hT, const float* __restrict__ sq,
    float* __restrict__ P, float* __restrict__ dinv) {
  int i0 = blockIdx.x * 8;
  int t = threadIdx.x;
  float h[8][6], si[8];
#pragma unroll
  for (int q = 0; q < 8; q++) {
    si[q] = sq[i0 + q];
#pragma unroll
    for (int r = 0; r < 6; r++) h[q][r] = hT[(size_t)r * NN + i0 + q];
  }
  float acc[8] = {0.f, 0.f, 0.f, 0.f, 0.f, 0.f, 0.f, 0.f};
  for (int j4 = t; j4 < NN / 4; j4 += 256) {
    int j = j4 * 4;
    float4 qv = *(const float4*)(sq + j);
    float4 v0 = *(const float4*)(hT + j);
    float4 v1 = *(const float4*)(hT + NN + j);
    float4 v2 = *(const float4*)(hT + 2 * NN + j);
    float4 v3 = *(const float4*)(hT + 3 * NN + j);
    float4 v4 = *(const float4*)(hT + 4 * NN + j);
    float4 v5 = *(const float4*)(hT + 5 * NN + j);
#pragma unroll
    for (int q = 0; q < 8; q++) {
      float p[4];
#pragma unroll
      for (int m = 0; m < 4; m++) {
        float dot = h[q][0] * ((const float*)&v0)[m] + h[q][1] * ((const float*)&v1)[m] +
                    h[q][2] * ((const float*)&v2)[m] + h[q][3] * ((const float*)&v3)[m] +
                    h[q][4] * ((const float*)&v4)[m] + h[q][5] * ((const float*)&v5)[m];
        float d = si[q] + ((const float*)&qv)[m] - 2.f * dot;
        p[m] = __expf(-0.5f * d);
        if (j + m != i0 + q) acc[q] += p[m];
      }
      float4 pv; pv.x = p[0]; pv.y = p[1]; pv.z = p[2]; pv.w = p[3];
      *(float4*)(P + (size_t)(i0 + q) * NN + j) = pv;
    }
  }
  __shared__ float red[256];
#pragma unroll
  for (int q = 0; q < 8; q++) {
    red[t] = acc[q];
    __syncthreads();
    for (int s = 128; s > 0; s >>= 1) {
      if (t < s) red[t] += red[t + s];
      __syncthreads();
    }
    if (t == 0) {
      float deg = red[0];
      dinv[i0 + q] = deg > 0.f ? rsqrtf(deg) : 0.f;
    }
    __syncthreads();
  }
}

// ---------------------------------------------------------------- smat (fp8, 8 rows/block)
__global__ __launch_bounds__(256) void smat_kernel(
    const float* __restrict__ hT, const float* __restrict__ sq,
    const float* __restrict__ dinv, unsigned int* __restrict__ S32) {
  int i0 = blockIdx.x * 8;
  int t = threadIdx.x;
  float h[8][6], si[8], dis[8];
#pragma unroll
  for (int q = 0; q < 8; q++) {
    si[q] = sq[i0 + q];
    dis[q] = -SSCALE * dinv[i0 + q];
#pragma unroll
    for (int r = 0; r < 6; r++) h[q][r] = hT[(size_t)r * NN + i0 + q];
  }
  for (int j4 = t; j4 < NN / 4; j4 += 256) {
    int j = j4 * 4;
    float4 qv = *(const float4*)(sq + j);
    float4 dj = *(const float4*)(dinv + j);
    float4 v0 = *(const float4*)(hT + j);
    float4 v1 = *(const float4*)(hT + NN + j);
    float4 v2 = *(const float4*)(hT + 2 * NN + j);
    float4 v3 = *(const float4*)(hT + 3 * NN + j);
    float4 v4 = *(const float4*)(hT + 4 * NN + j);
    float4 v5 = *(const float4*)(hT + 5 * NN + j);
#pragma unroll
    for (int q = 0; q < 8; q++) {
      float s[4];
#pragma unroll
      for (int m = 0; m < 4; m++) {
        float dot = h[q][0] * ((const float*)&v0)[m] + h[q][1] * ((const float*)&v1)[m] +
                    h[q][2] * ((const float*)&v2)[m] + h[q][3] * ((const float*)&v3)[m] +
                    h[q][4] * ((const float*)&v4)[m] + h[q][5] * ((const float*)&v5)[m];
        float d = si[q] + ((const float*)&qv)[m] - 2.f * dot;
        float p = __expf(-0.5f * d);
        s[m] = dis[q] * p * ((const float*)&dj)[m];
        if (j + m == i0 + q) s[m] = 0.f;
      }
      S32[(size_t)(i0 + q) * (NN / 4) + j4] = pack4_fp8(s[0], s[1], s[2], s[3]);
    }
  }
}

// ---------------------------------------------------------------- gemm (fp8, 3-buf ring, counted vmcnt)
__global__ __launch_bounds__(256, 3) void gemm_kernel(
    const unsigned char* __restrict__ S, const unsigned char* __restrict__ XT,
    unsigned char* __restrict__ partial) {
  __shared__ unsigned char As[3][128 * 64];
  __shared__ unsigned char Bs[3][128 * 64];
  // bijective XCD swizzle: 768 = 8 XCDs x 96
  int orig = blockIdx.x;
  int wgid = (orig & 7) * 96 + (orig >> 3);
  int mb = wgid % 48;
  int ks = wgid / 48;
  int t = threadIdx.x;
  int w = t >> 6, l = t & 63;
  int wr = w >> 1, wc = w & 1;
  int lr = l & 15, lg = l >> 4;
  int row0 = mb * 128;
  int k0 = ks * KC;

  int r16 = l >> 2;
  int key = ((r16 & 3) + ((r16 >> 2) & 3)) & 3;
  int us = (l & 3) ^ key;
  const unsigned char* gA = S + (size_t)(row0 + w * 32 + r16) * NN + k0 + us * 16;
  const unsigned char* gB = XT + (size_t)(w * 32 + r16) * NN + k0 + us * 16;
  int lofs = (w * 32) * 64;

  f32x4 acc[4][4];
#pragma unroll
  for (int a = 0; a < 4; a++)
#pragma unroll
    for (int b = 0; b < 4; b++) acc[a][b] = (f32x4){0.f, 0.f, 0.f, 0.f};

#define STAGE(buf, bk)                                              \
  do {                                                              \
    gload16(gA + (bk), &As[buf][lofs]);                             \
    gload16(gA + (size_t)16 * NN + (bk), &As[buf][lofs + 16 * 64]); \
    gload16(gB + (bk), &Bs[buf][lofs]);                             \
    gload16(gB + (size_t)16 * NN + (bk), &Bs[buf][lofs + 16 * 64]); \
  } while (0)

  STAGE(0, 0);
  STAGE(1, BK);
  for (int step = 0; step < NSTEPS; step++) {
    if (step + 2 < NSTEPS) {
      STAGE((step + 2) % 3, (step + 2) * BK);
      asm volatile("s_waitcnt vmcnt(8)" ::: "memory");
    } else if (step + 1 < NSTEPS) {
      asm volatile("s_waitcnt vmcnt(4)" ::: "memory");
    } else {
      asm volatile("s_waitcnt vmcnt(0)" ::: "memory");
    }
    asm volatile("s_barrier" ::: "memory");
    int bi = step % 3;
#pragma unroll
    for (int kk2 = 0; kk2 < BK; kk2 += 32) {
      long af[4], bf[4];
#pragma unroll
      for (int i = 0; i < 4; i++) {
        int ra = wr * 64 + i * 16 + lr;
        int rb = wc * 64 + i * 16 + lr;
        int off = kk2 + lg * 8;
        int ka = ((ra & 3) + ((ra >> 2) & 3)) & 3;
        int kb = ((rb & 3) + ((rb >> 2) & 3)) & 3;
        int pa = ra * 64 + ((((off >> 4) ^ ka) << 4) | (off & 8));
        int pb = rb * 64 + ((((off >> 4) ^ kb) << 4) | (off & 8));
        af[i] = *(const long*)(&As[bi][pa]);
        bf[i] = *(const long*)(&Bs[bi][pb]);
      }
#pragma unroll
      for (int ar = 0; ar < 4; ar++)
#pragma unroll
        for (int bn = 0; bn < 4; bn++)
          acc[ar][bn] = __builtin_amdgcn_mfma_f32_16x16x32_fp8_fp8(
              af[ar], bf[bn], acc[ar][bn], 0, 0, 0);
    }
    asm volatile("s_barrier" ::: "memory");
  }
#undef STAGE

  // C/D layout: col = lane&15, row-in-16 = lg*4 + r ; partial stored fp8 (/128)
  unsigned char* pbase = partial + (size_t)ks * NN * F1;
#pragma unroll
  for (int ar = 0; ar < 4; ar++) {
    int rowo = row0 + wr * 64 + ar * 16 + lg * 4;
#pragma unroll
    for (int bn = 0; bn < 4; bn++) {
      int colo = wc * 64 + bn * 16 + lr;
#pragma unroll
      for (int r = 0; r < 4; r++)
        pbase[(size_t)(rowo + r) * F1 + colo] = f2fp8(acc[ar][bn][r] * PSCALE_INV);
    }
  }
}

// ---------------------------------------------------------------- finalize (fp8 partial)
__global__ __launch_bounds__(256) void finalize_kernel(
    const unsigned int* __restrict__ partial, const float4* __restrict__ prevprev,
    float4* __restrict__ TxOut, unsigned int* __restrict__ XT8, int dsub) {
  const int TOT4 = NN * F1 / 4;
  int t = threadIdx.x;
  int rquad = t >> 5, c4 = t & 31;
  int row0 = blockIdx.x * 32 + rquad * 4;
  float g[4][4];
#pragma unroll
  for (int rr = 0; rr < 4; rr++) {
    int fidx = (row0 + rr) * 32 + c4;
    float a0 = 0.f, a1 = 0.f, a2 = 0.f, a3 = 0.f;
#pragma unroll
    for (int s = 0; s < KSPLIT; s++) {
      unsigned int v = partial[(size_t)s * TOT4 + fidx];
      a0 += fp8tof<0>(v); a1 += fp8tof<1>(v);
      a2 += fp8tof<2>(v); a3 += fp8tof<3>(v);
    }
    a0 *= FSCALE; a1 *= FSCALE; a2 *= FSCALE; a3 *= FSCALE;
    if (dsub) {
      float4 q = prevprev[fidx];
      a0 = 2.f * a0 - q.x; a1 = 2.f * a1 - q.y;
      a2 = 2.f * a2 - q.z; a3 = 2.f * a3 - q.w;
    }
    float4 o; o.x = a0; o.y = a1; o.z = a2; o.w = a3;
    TxOut[fidx] = o;
    g[rr][0] = a0; g[rr][1] = a1; g[rr][2] = a2; g[rr][3] = a3;
  }
#pragma unroll
  for (int j = 0; j < 4; j++) {
    unsigned int pk = pack4_fp8(g[0][j], g[1][j], g[2][j], g[3][j]);
    XT8[(((size_t)(c4 * 4 + j)) * NN + row0) >> 2] = pk;
  }
}

// ---------------------------------------------------------------- epilogue (384 blocks x 16 rows)
__global__ __launch_bounds__(256) void out_kernel(
    const float* __restrict__ Tx, const float* __restrict__ Wcat,
    const float* __restrict__ b3, const float* __restrict__ b6,
    const float* __restrict__ b9,
    const float* __restrict__ Wl, const float* __restrict__ bl,
    float* __restrict__ x_out, float* __restrict__ last_out) {
  __shared__ float WS[128 * 48];
  __shared__ float TxS[16][129];
  __shared__ float lo[16][48];
  __shared__ float lg[16][16];
  __shared__ float le[16][16];
  __shared__ float WlS[48 * 16];
  __shared__ float blS[16];
  int t = threadIdx.x;
  int row0 = blockIdx.x * 16;
  int rg = t >> 4;
  int cg = t & 15;
  float acc[3] = {0.f, 0.f, 0.f};
  for (int i = t; i < 768; i += 256) WlS[i] = Wl[i];
  if (t < 16) blS[t] = bl[t];
  for (int k = 0; k < 9; k++) {
    for (int i = t; i < 6144; i += 256) WS[i] = Wcat[k * 6144 + i];
    for (int i = t; i < 2048; i += 256) {
      int r = i >> 7, j = i & 127;
      TxS[r][j] = Tx[((size_t)k * NN + row0 + r) * F1 + j];
    }
    __syncthreads();
#pragma unroll 4
    for (int j = 0; j < 128; j++) {
      float t0 = TxS[rg][j];
      const float* wp = &WS[j * 48 + 3 * cg];
      acc[0] += t0 * wp[0]; acc[1] += t0 * wp[1]; acc[2] += t0 * wp[2];
    }
    __syncthreads();
  }
#pragma unroll
  for (int cc = 0; cc < 3; cc++) {
    int c = 3 * cg + cc;
    float bias = c < 16 ? b3[c] : (c < 32 ? b6[c - 16] : b9[c - 32]);
    float v = acc[cc] + bias;
    lo[rg][c] = v;
    last_out[(size_t)(row0 + rg) * 48 + c] = v;
  }
  __syncthreads();
  {
    int r = t >> 4, c = t & 15;
    float lgt = blS[c];
#pragma unroll 8
    for (int j = 0; j < 48; j++) lgt += lo[r][j] * WlS[j * 16 + c];
    lg[r][c] = lgt;
  }
  __syncthreads();
  {
    int r = t >> 4, c = t & 15;
    float mx = lg[r][0];
#pragma unroll
    for (int j = 1; j < 16; j++) mx = fmaxf(mx, lg[r][j]);
    le[r][c] = __expf(lg[r][c] - mx);
  }
  __syncthreads();
  {
    int r = t >> 4, c = t & 15;
    float sum = 0.f;
#pragma unroll
    for (int j = 0; j < 16; j++) sum += le[r][j];
    x_out[(size_t)(row0 + r) * 16 + c] = le[r][c] / sum;
  }
}

// ---------------------------------------------------------------- misc copies + Wcat build
__global__ __launch_bounds__(256) void copy_kernel(
    const int* __restrict__ tr, const int* __restrict__ val,
    const float* __restrict__ x0, float* __restrict__ tr_out,
    float* __restrict__ val_out, float* __restrict__ x0_out,
    const float* __restrict__ W3, const float* __restrict__ W6,
    const float* __restrict__ W9, float* __restrict__ Wcat) {
  int i = blockIdx.x * 256 + threadIdx.x;
  if (i < 4000) tr_out[i] = (float)tr[i];
  if (i < 1000) val_out[i] = (float)val[i];
  if (i < NN * 64) x0_out[i] = x0[i];
  if (i < 9 * 128 * 48) {
    int c = i % 48;
    int j = (i / 48) % 128;
    int k = i / (48 * 128);
    float v = 0.f;
    if (c < 16) {
      if (k < 3) v = W3[(k * 128 + j) * 16 + c];
    } else if (c < 32) {
      if (k < 6) v = W6[(k * 128 + j) * 16 + (c - 16)];
    } else {
      v = W9[(k * 128 + j) * 16 + (c - 32)];
    }
    Wcat[i] = v;
  }
}

extern "C" void kernel_launch(void* const* d_in, const int* in_sizes, int n_in,
                              void* d_out, int out_size, void* d_ws, size_t ws_size,
                              hipStream_t stream) {
  const float* x5 = (const float*)d_in[0];
  const float* x0 = (const float*)d_in[1];
  const int* tr = (const int*)d_in[2];
  const int* val = (const int*)d_in[3];
  const float* W_gat = (const float*)d_in[4];
  const float* b_gat = (const float*)d_in[5];
  const float* W_lin = (const float*)d_in[6];
  const float* b_lin = (const float*)d_in[7];
  const float* W3 = (const float*)d_in[8];
  const float* b3 = (const float*)d_in[9];
  const float* W6 = (const float*)d_in[10];
  const float* b6 = (const float*)d_in[11];
  const float* W9 = (const float*)d_in[12];
  const float* b9 = (const float*)d_in[13];
  const float* Wl = (const float*)d_in[14];
  const float* bl = (const float*)d_in[15];

  float* out = (float*)d_out;
  float* x_out = out;
  float* tr_out = x_out + (size_t)NN * 16;
  float* val_out = tr_out + 4000;
  float* P = val_out + 1000;
  float* last_out = P + (size_t)NN * NN;
  float* x0_out = last_out + (size_t)NN * 48;

  char* w = (char*)d_ws;
  unsigned char* Sb = (unsigned char*)w;    w += (size_t)NN * NN;
  float* Tx = (float*)w;                    w += (size_t)9 * NN * F1 * 4;
  unsigned char* partial = (unsigned char*)w; w += (size_t)KSPLIT * NN * F1;
  unsigned char* XTa = (unsigned char*)w;   w += (size_t)NN * F1;
  unsigned char* XTb = (unsigned char*)w;   w += (size_t)NN * F1;
  float* hT = (float*)w;                    w += (size_t)6 * NN * 4;
  float* sq = (float*)w;                    w += (size_t)NN * 4;
  float* dinv = (float*)w;                  w += (size_t)NN * 4;
  float* Wcat = (float*)w;                  w += (size_t)9 * 128 * 48 * 4;

  prep_kernel<<<NN, 128, 0, stream>>>(x5, x0, W_gat, b_gat, W_lin, b_lin, hT, sq,
                                      Tx, XTa);
  prob_kernel<<<NN / 8, 256, 0, stream>>>(hT, sq, P, dinv);
  smat_kernel<<<NN / 8, 256, 0, stream>>>(hT, sq, dinv, (unsigned int*)Sb);
  copy_kernel<<<1536, 256, 0, stream>>>(tr, val, x0, tr_out, val_out, x0_out,
                                        W3, W6, W9, Wcat);

  unsigned char* xin = XTa;
  unsigned char* xout = XTb;
  for (int k = 1; k <= 8; k++) {
    gemm_kernel<<<768, 256, 0, stream>>>(Sb, xin, partial);
    const float4* pp = (const float4*)(Tx + (size_t)(k >= 2 ? k - 2 : 0) * NN * F1);
    finalize_kernel<<<192, 256, 0, stream>>>((const unsigned int*)partial, pp,
                                             (float4*)(Tx + (size_t)k * NN * F1),
                                             (unsigned int*)xout, k >= 2 ? 1 : 0);
    unsigned char* tmp = xin; xin = xout; xout = tmp;
  }

  out_kernel<<<384, 256, 0, stream>>>(Tx, Wcat, b3, b6, b9, Wl, bl, x_out,
                                      last_out);
}